// Round 7
// baseline (278.568 us; speedup 1.0000x reference)
//
#include <hip/hip_runtime.h>
#include <hip/hip_bf16.h>
#include <math.h>

// ---------------------------------------------------------------------------
// DualHeadGAT R7: multi-edge-per-wave gathers (l1: 2 edges/instr via 16B/lane,
// l2: 4 edges/instr via 8B/lane), precomputed per-edge softmax coefficients,
// bf16 feature gathers, MFMA GEMMs with fused att dots + in-register f32->bf16
// A conversion (layer 1), CSR aggregation, implicit self-loops, deferred
// softmax normalization (exact). N=50000, IN=128, E=800000.
// ---------------------------------------------------------------------------

#define LRELU_SLOPE 0.2f

typedef __attribute__((ext_vector_type(8))) short short8;   // 8 bf16 = 4 VGPR
typedef __attribute__((ext_vector_type(4))) float f32x4;

__device__ inline ushort f2bf(float f) {            // RNE f32 -> bf16
    uint u = __float_as_uint(f);
    return (ushort)((u + 0x7FFFu + ((u >> 16) & 1u)) >> 16);
}
__device__ inline float bf2f(ushort u) {
    return __uint_as_float(((uint)u) << 16);
}

// ------- pre-fragment W[K][16J] (f32, row-major) into MFMA B-frag order ----
__global__ __launch_bounds__(256)
void prefrag(const float* __restrict__ W, ushort* __restrict__ out,
             int J, int T, int ldn)
{
    int tid = blockIdx.x * blockDim.x + threadIdx.x;
    if (tid >= J * T * 64) return;
    int l = tid & 63, jt = tid >> 6;
    int t = jt % T, j = jt / T;
    int n = j * 16 + (l & 15);
    int k0 = t * 32 + (l >> 4) * 8;
    ushort o[8];
    #pragma unroll
    for (int b = 0; b < 8; ++b) o[b] = f2bf(W[(size_t)(k0 + b) * ldn + n]);
    *(short8*)(out + (size_t)tid * 8) = *(short8*)o;
}

// ---------------- MFMA GEMM, row-panel, LDS-free, bf16 output --------------
template<int J, int T, int H, bool AF32>
__global__ __launch_bounds__(256)
void gemm_mfma(const void* __restrict__ Araw, const ushort* __restrict__ Bf,
               ushort* __restrict__ Cbf, const float* __restrict__ attS,
               const float* __restrict__ attD, float* __restrict__ as_,
               float* __restrict__ ad_, int M)
{
    constexpr int K = 32 * T;
    constexpr int NN = 16 * J;
    const int l = threadIdx.x & 63;
    const int wid = blockIdx.x * (blockDim.x >> 6) + (threadIdx.x >> 6);
    const int base = wid * 16;
    if (base >= M) return;
    const int lm = l & 15, lg = l >> 4;

    short8 a[T];
    if constexpr (AF32) {
        const float* ap = (const float*)Araw + (size_t)(base + lm) * K + lg * 8;
        #pragma unroll
        for (int t = 0; t < T; ++t) {
            float4 v0 = *(const float4*)(ap + t * 32);
            float4 v1 = *(const float4*)(ap + t * 32 + 4);
            ushort o[8];
            o[0] = f2bf(v0.x); o[1] = f2bf(v0.y); o[2] = f2bf(v0.z); o[3] = f2bf(v0.w);
            o[4] = f2bf(v1.x); o[5] = f2bf(v1.y); o[6] = f2bf(v1.z); o[7] = f2bf(v1.w);
            a[t] = *(short8*)o;
        }
    } else {
        const ushort* ap = (const ushort*)Araw + (size_t)(base + lm) * K + lg * 8;
        #pragma unroll
        for (int t = 0; t < T; ++t) a[t] = *(const short8*)(ap + t * 32);
    }

    f32x4 acc[J];
    #pragma unroll
    for (int j = 0; j < J; ++j) acc[j] = (f32x4){0.f, 0.f, 0.f, 0.f};

    const ushort* bp = Bf + (size_t)l * 8;
    #pragma unroll
    for (int j = 0; j < J; ++j)
        #pragma unroll
        for (int t = 0; t < T; ++t) {
            short8 b = *(const short8*)(bp + (size_t)(j * T + t) * 512);
            acc[j] = __builtin_amdgcn_mfma_f32_16x16x32_bf16(a[t], b, acc[j], 0, 0, 0);
        }

    // epilogue: store bf16 C + fused attention dots (f32 precision)
    float sp[H][4], dp[H][4];
    #pragma unroll
    for (int h = 0; h < H; ++h)
        #pragma unroll
        for (int r = 0; r < 4; ++r) { sp[h][r] = 0.f; dp[h][r] = 0.f; }

    #pragma unroll
    for (int j = 0; j < J; ++j) {
        const int h = j / (J / H);
        const int coff = (j % (J / H)) * 16 + lm;     // col within head
        float ws = attS[h * 64 + coff];
        float wd = attD[h * 64 + coff];
        #pragma unroll
        for (int r = 0; r < 4; ++r) {
            int row = base + lg * 4 + r;
            Cbf[(size_t)row * NN + j * 16 + lm] = f2bf(acc[j][r]);
            sp[h][r] = fmaf(acc[j][r], ws, sp[h][r]);
            dp[h][r] = fmaf(acc[j][r], wd, dp[h][r]);
        }
    }
    #pragma unroll
    for (int h = 0; h < H; ++h)
        #pragma unroll
        for (int r = 0; r < 4; ++r) {
            float s = sp[h][r], d = dp[h][r];
            s += __shfl_xor(s, 1); d += __shfl_xor(d, 1);
            s += __shfl_xor(s, 2); d += __shfl_xor(d, 2);
            s += __shfl_xor(s, 4); d += __shfl_xor(d, 4);
            s += __shfl_xor(s, 8); d += __shfl_xor(d, 8);
            if (lm == 0) {
                int row = base + lg * 4 + r;
                as_[row * H + h] = s;
                ad_[row * H + h] = d;
            }
        }
}

// ---------------- CSR build (real edges only; self-loops implicit) ---------
__global__ __launch_bounds__(256)
void degree_hist(const int* __restrict__ edst, int* __restrict__ deg, int E)
{
    int i = blockIdx.x * blockDim.x + threadIdx.x;
    if (i < E) atomicAdd(&deg[edst[i]], 1);
}

// single-block exclusive scan, 4 elems/thread; also zeroes cursor
__global__ __launch_bounds__(1024)
void scan_rowptr(const int* __restrict__ deg, int* __restrict__ rowptr,
                 int* __restrict__ cursor, int N)
{
    __shared__ int wsums[16];
    __shared__ int s_carry;
    const int tid = threadIdx.x, lane = tid & 63, wid = tid >> 6;
    if (tid == 0) s_carry = 0;
    __syncthreads();
    const int N4 = N >> 2;
    for (int base = 0; base < N4; base += 1024) {
        int i4 = base + tid;
        int4 v = (i4 < N4) ? ((const int4*)deg)[i4] : make_int4(0, 0, 0, 0);
        int tsum = v.x + v.y + v.z + v.w;
        int sc = tsum;
        #pragma unroll
        for (int off = 1; off < 64; off <<= 1) {
            int t = __shfl_up(sc, off);
            if (lane >= off) sc += t;
        }
        if (lane == 63) wsums[wid] = sc;
        __syncthreads();
        if (wid == 0) {
            int wv = (lane < 16) ? wsums[lane] : 0;
            #pragma unroll
            for (int off = 1; off < 16; off <<= 1) {
                int t = __shfl_up(wv, off);
                if (lane >= off) wv += t;
            }
            if (lane < 16) wsums[lane] = wv;
        }
        __syncthreads();
        int wbase = (wid > 0) ? wsums[wid - 1] : 0;
        int excl = s_carry + wbase + sc - tsum;
        if (i4 < N4) {
            int4 o;
            o.x = excl; o.y = excl + v.x; o.z = o.y + v.y; o.w = o.z + v.z;
            ((int4*)rowptr)[i4] = o;
            ((int4*)cursor)[i4] = make_int4(0, 0, 0, 0);
        }
        __syncthreads();
        if (tid == 0) s_carry += wsums[15];
        __syncthreads();
    }
    if (tid == 0) rowptr[N] = s_carry;
}

__global__ __launch_bounds__(256)
void scatter_edges(const int* __restrict__ esrc, const int* __restrict__ edst,
                   const int* __restrict__ rowptr, int* __restrict__ cursor,
                   int* __restrict__ csr_src, int* __restrict__ csr_dst, int E)
{
    int i = blockIdx.x * blockDim.x + threadIdx.x;
    if (i >= E) return;
    int s = esrc[i], d = edst[i];
    int pos = rowptr[d] + atomicAdd(&cursor[d], 1);
    csr_src[pos] = s;
    csr_dst[pos] = d;
}

// ---- per-edge softmax coefficients, layer 1 (4 heads), streaming ----------
__global__ __launch_bounds__(256)
void edge_coef_l1(const int* __restrict__ csr_src, const int* __restrict__ csr_dst,
                  const float* __restrict__ as_, const float* __restrict__ ad_,
                  float* __restrict__ p1, int E)
{
    int i = blockIdx.x * blockDim.x + threadIdx.x;
    if (i >= E) return;
    int s = csr_src[i], d = csr_dst[i];
    float4 a = *(const float4*)(as_ + (size_t)s * 4);
    float4 b = *(const float4*)(ad_ + (size_t)d * 4);
    float4 o;
    float e0 = a.x + b.x; e0 = e0 > 0.f ? e0 : LRELU_SLOPE * e0; o.x = __expf(e0);
    float e1 = a.y + b.y; e1 = e1 > 0.f ? e1 : LRELU_SLOPE * e1; o.y = __expf(e1);
    float e2 = a.z + b.z; e2 = e2 > 0.f ? e2 : LRELU_SLOPE * e2; o.z = __expf(e2);
    float e3 = a.w + b.w; e3 = e3 > 0.f ? e3 : LRELU_SLOPE * e3; o.w = __expf(e3);
    *(float4*)(p1 + (size_t)i * 4) = o;
}

// ---- per-edge softmax coefficients, layer 2 (1 head), streaming -----------
__global__ __launch_bounds__(256)
void edge_coef_l2(const int* __restrict__ csr_src, const int* __restrict__ csr_dst,
                  const float* __restrict__ as_, const float* __restrict__ ad_,
                  float* __restrict__ p2, int E)
{
    int i = blockIdx.x * blockDim.x + threadIdx.x;
    if (i >= E) return;
    float e0 = as_[csr_src[i]] + ad_[csr_dst[i]];
    e0 = e0 > 0.f ? e0 : LRELU_SLOPE * e0;
    p2[i] = __expf(e0);
}

// -------- layer-1 aggregation: wave per dst; 2 edges per load instr --------
// 16B/lane: 32 lanes cover one 512B row; half-wave per edge slot.
__global__ __launch_bounds__(256)
void aggregate_l1(const int* __restrict__ rowptr, const int* __restrict__ csr_src,
                  const float* __restrict__ p1, const ushort* __restrict__ h1,
                  const float* __restrict__ as_, const float* __restrict__ ad_,
                  const float* __restrict__ bias, ushort* __restrict__ outbf, int N)
{
    int w = (blockIdx.x * blockDim.x + threadIdx.x) >> 6;
    int lane = threadIdx.x & 63;
    if (w >= N) return;
    const int half = lane >> 5;          // edge parity slot (0/1)
    const int hl   = lane & 31;          // 32 lanes x 8 cols = 256 cols
    const int c0   = hl << 3;
    const int head = hl >> 3;            // 4 heads x 8 lanes

    float acc[8];
    float dsum;
    {   // implicit self-loop (counted in half 0 only; halves merge at end)
        float el = as_[w * 4 + head] + ad_[w * 4 + head];
        el = el > 0.f ? el : LRELU_SLOPE * el;
        float p = half ? 0.f : __expf(el);
        ushort u8[8];
        *(short8*)u8 = *(const short8*)(h1 + (size_t)w * 256 + c0);
        #pragma unroll
        for (int k = 0; k < 8; ++k) acc[k] = p * bf2f(u8[k]);
        dsum = p;
    }

    int e = rowptr[w];
    const int e1 = rowptr[w + 1];
    const int eL = e1 - 1;
    while (e < e1) {
        #pragma unroll
        for (int u = 0; u < 4; ++u) {    // 8 edges in flight per wave
            int m = e + 2 * u + half;
            int idx = m <= eL ? m : eL;  // clamped phantom -> L1 hit
            int s = csr_src[idx];
            float p = m <= eL ? p1[(size_t)idx * 4 + head] : 0.f;
            ushort u8[8];
            *(short8*)u8 = *(const short8*)(h1 + (size_t)s * 256 + c0);
            #pragma unroll
            for (int k = 0; k < 8; ++k) acc[k] = fmaf(p, bf2f(u8[k]), acc[k]);
            dsum += p;
        }
        e += 8;
    }

    // merge the two half-wave accumulators
    dsum += __shfl_xor(dsum, 32);
    #pragma unroll
    for (int k = 0; k < 8; ++k) acc[k] += __shfl_xor(acc[k], 32);

    const float inv = 1.f / (dsum + 1e-16f);
    const float4 b0 = *(const float4*)(bias + c0);
    const float4 b1 = *(const float4*)(bias + c0 + 4);
    float bb[8] = {b0.x, b0.y, b0.z, b0.w, b1.x, b1.y, b1.z, b1.w};
    ushort o[8];
    #pragma unroll
    for (int k = 0; k < 8; ++k) {
        float v = acc[k] * inv + bb[k];
        v = v > 0.f ? v : expm1f(v);
        o[k] = f2bf(v);
    }
    if (half == 0)
        *(short8*)(outbf + (size_t)w * 256 + c0) = *(short8*)o;
}

// -------- layer-2 aggregation + scoring head; 4 edges per load instr -------
// 8B/lane: 16 lanes cover one 128B row; quarter-wave per edge slot.
__global__ __launch_bounds__(256)
void aggregate_l2(const int* __restrict__ rowptr, const int* __restrict__ csr_src,
                  const float* __restrict__ p2, const ushort* __restrict__ h2,
                  const float* __restrict__ as_, const float* __restrict__ ad_,
                  const float* __restrict__ b2, const float* __restrict__ Wsv,
                  const float* __restrict__ bs, float* __restrict__ hout,
                  float* __restrict__ scores, int N)
{
    int w = (blockIdx.x * blockDim.x + threadIdx.x) >> 6;
    int lane = threadIdx.x & 63;
    if (w >= N) return;
    const int q  = lane >> 4;            // edge slot (0..3)
    const int ql = lane & 15;            // 16 lanes x 4 cols = 64 cols
    const int c0 = ql << 2;

    float acc[4];
    float dsum;
    {   // implicit self-loop (quarter 0 only)
        float el = as_[w] + ad_[w];
        el = el > 0.f ? el : LRELU_SLOPE * el;
        float p = (q == 0) ? __expf(el) : 0.f;
        ushort u4[4];
        *(ushort4*)u4 = *(const ushort4*)(h2 + (size_t)w * 64 + c0);
        #pragma unroll
        for (int k = 0; k < 4; ++k) acc[k] = p * bf2f(u4[k]);
        dsum = p;
    }

    int e = rowptr[w];
    const int e1 = rowptr[w + 1];
    const int eL = e1 - 1;
    while (e < e1) {
        #pragma unroll
        for (int u = 0; u < 2; ++u) {    // 8 edges in flight per wave
            int m = e + 4 * u + q;
            int idx = m <= eL ? m : eL;
            int s = csr_src[idx];
            float p = m <= eL ? p2[idx] : 0.f;
            ushort u4[4];
            *(ushort4*)u4 = *(const ushort4*)(h2 + (size_t)s * 64 + c0);
            #pragma unroll
            for (int k = 0; k < 4; ++k) acc[k] = fmaf(p, bf2f(u4[k]), acc[k]);
            dsum += p;
        }
        e += 8;
    }

    // merge the four quarter-wave accumulators
    dsum += __shfl_xor(dsum, 16); dsum += __shfl_xor(dsum, 32);
    #pragma unroll
    for (int k = 0; k < 4; ++k) {
        acc[k] += __shfl_xor(acc[k], 16);
        acc[k] += __shfl_xor(acc[k], 32);
    }

    const float inv = 1.f / (dsum + 1e-16f);
    const float4 bb = *(const float4*)(b2 + c0);
    const float4 ww = *(const float4*)(Wsv + c0);
    float v0 = acc[0] * inv + bb.x; v0 = v0 > 0.f ? v0 : expm1f(v0);
    float v1 = acc[1] * inv + bb.y; v1 = v1 > 0.f ? v1 : expm1f(v1);
    float v2 = acc[2] * inv + bb.z; v2 = v2 > 0.f ? v2 : expm1f(v2);
    float v3 = acc[3] * inv + bb.w; v3 = v3 > 0.f ? v3 : expm1f(v3);
    if (q == 0)
        *(float4*)(hout + (size_t)w * 64 + c0) = make_float4(v0, v1, v2, v3);
    float sc = fmaf(v0, ww.x, fmaf(v1, ww.y, fmaf(v2, ww.z, v3 * ww.w)));
    sc += __shfl_xor(sc, 1); sc += __shfl_xor(sc, 2);
    sc += __shfl_xor(sc, 4); sc += __shfl_xor(sc, 8);
    if (lane == 0) scores[w] = sc + bs[0];
}

// ---------------------------------------------------------------------------
extern "C" void kernel_launch(void* const* d_in, const int* in_sizes, int n_in,
                              void* d_out, int out_size, void* d_ws, size_t ws_size,
                              hipStream_t stream)
{
    const float* x    = (const float*)d_in[0];
    const int*   ei   = (const int*)d_in[1];
    const float* W1   = (const float*)d_in[2];
    const float* as1w = (const float*)d_in[3];
    const float* ad1w = (const float*)d_in[4];
    const float* b1   = (const float*)d_in[5];
    const float* W2   = (const float*)d_in[6];
    const float* as2w = (const float*)d_in[7];
    const float* ad2w = (const float*)d_in[8];
    const float* b2   = (const float*)d_in[9];
    const float* Ws   = (const float*)d_in[10];
    const float* bs   = (const float*)d_in[11];

    const int N  = in_sizes[0] / 128;   // 50000
    const int E  = in_sizes[1] / 2;     // 800000
    const int* esrc = ei;
    const int* edst = ei + E;

    // ---- workspace layout (16B-aligned chunks) ----
    ushort* h1bf  = (ushort*)d_ws;                       // N*256 bf16
    ushort* hl1bf = h1bf + (size_t)N * 256;              // N*256 bf16
    ushort* h2bf  = hl1bf + (size_t)N * 256;             // N*64 bf16
    ushort* bfr1  = h2bf + (size_t)N * 64;               // 32768
    ushort* bfr2  = bfr1 + 32768;                        // 16384
    float*  as1   = (float*)(bfr2 + 16384);              // N*4
    float*  ad1   = as1 + (size_t)N * 4;                 // N*4
    float*  as2   = ad1 + (size_t)N * 4;                 // N
    float*  ad2   = as2 + N;                             // N
    float*  p1    = ad2 + N;                             // E*4
    float*  p2    = p1 + (size_t)E * 4;                  // E
    int*    deg    = (int*)(p2 + E);                     // N
    int*    cursor = deg + N;                            // N
    int*    rowptr = cursor + N;                         // N+1 (+pad)
    int*    csr_src= rowptr + N + 4;                     // E
    int*    csr_dst= csr_src + E;                        // E

    float* hout   = (float*)d_out;                       // N*64
    float* scores = hout + (size_t)N * 64;               // N

    // ---------------- CSR build (shared by both layers) ----------------
    hipMemsetAsync(deg, 0, (size_t)N * sizeof(int), stream);
    degree_hist<<<(E + 255) / 256, 256, 0, stream>>>(edst, deg, E);
    scan_rowptr<<<1, 1024, 0, stream>>>(deg, rowptr, cursor, N);
    scatter_edges<<<(E + 255) / 256, 256, 0, stream>>>(
        esrc, edst, rowptr, cursor, csr_src, csr_dst, E);

    // ---------------- weight pre-fragmentation -------
    prefrag<<<(16 * 4 * 64 + 255) / 256, 256, 0, stream>>>(W1, bfr1, 16, 4, 256);
    prefrag<<<(4 * 8 * 64 + 255) / 256, 256, 0, stream>>>(W2, bfr2, 4, 8, 64);

    // ---------------- layer 1 ----------------
    gemm_mfma<16, 4, 4, true><<<(N / 16 + 3) / 4, 256, 0, stream>>>(
        x, bfr1, h1bf, as1w, ad1w, as1, ad1, N);
    edge_coef_l1<<<(E + 255) / 256, 256, 0, stream>>>(
        csr_src, csr_dst, as1, ad1, p1, E);
    aggregate_l1<<<((size_t)N * 64 + 255) / 256, 256, 0, stream>>>(
        rowptr, csr_src, p1, h1bf, as1, ad1, b1, hl1bf, N);

    // ---------------- layer 2 ----------------
    gemm_mfma<4, 8, 1, false><<<(N / 16 + 3) / 4, 256, 0, stream>>>(
        hl1bf, bfr2, h2bf, as2w, ad2w, as2, ad2, N);
    edge_coef_l2<<<(E + 255) / 256, 256, 0, stream>>>(
        csr_src, csr_dst, as2, ad2, p2, E);
    aggregate_l2<<<((size_t)N * 64 + 255) / 256, 256, 0, stream>>>(
        rowptr, csr_src, p2, h2bf, as2, ad2, b2, Ws, bs, hout, scores, N);
}